// Round 1
// baseline (67.672 us; speedup 1.0000x reference)
//
#include <hip/hip_runtime.h>
#include <stdint.h>

#define NSTRUCT 8
#define NROWS   1024
#define DD      128

typedef short bf16x8 __attribute__((ext_vector_type(8)));  // 8 bf16 (4 VGPRs)
typedef float f32x4  __attribute__((ext_vector_type(4)));  // 4 fp32 acc

// ---------------------------------------------------------------------------
// Threefry2x32-20, JAX partitionable path: bits = out0 ^ out1 (verified
// earlier session, absmax 0.0 vs jax reference for the Bernoulli mask).
// u = bitcast((bits>>9)|0x3f800000) - 1.0
// ---------------------------------------------------------------------------
__device__ __forceinline__ uint32_t rotl32(uint32_t x, uint32_t d) {
  return (x << d) | (x >> (32u - d));
}

__device__ __forceinline__ uint32_t threefry_bits(uint32_t i) {
  const uint32_t ks0 = 0u;
  const uint32_t ks1 = 42u;
  const uint32_t ks2 = 0x1BD11BDAu ^ ks0 ^ ks1;
  uint32_t x0 = 0u + ks0;   // counts_hi = 0
  uint32_t x1 = i  + ks1;   // counts_lo = flat (o,p,c) index
#define TF_RND(r) { x0 += x1; x1 = rotl32(x1, r); x1 ^= x0; }
  TF_RND(13) TF_RND(15) TF_RND(26) TF_RND(6)
  x0 += ks1; x1 += ks2 + 1u;
  TF_RND(17) TF_RND(29) TF_RND(16) TF_RND(24)
  x0 += ks2; x1 += ks0 + 2u;
  TF_RND(13) TF_RND(15) TF_RND(26) TF_RND(6)
  x0 += ks0; x1 += ks1 + 3u;
  TF_RND(17) TF_RND(29) TF_RND(16) TF_RND(24)
  x0 += ks1; x1 += ks2 + 4u;
  TF_RND(13) TF_RND(15) TF_RND(26) TF_RND(6)
  x0 += ks2; x1 += ks0 + 5u;
#undef TF_RND
  return x0 ^ x1;
}

__device__ __forceinline__ uint16_t f32_to_bf16_rne(float v) {
  uint32_t fb = __float_as_uint(v);
  uint32_t lsb = (fb >> 16) & 1u;
  return (uint16_t)((fb + 0x7fffu + lsb) >> 16);
}

// ---------------------------------------------------------------------------
// Fused kernel: one launch, zero workspace.
// Grid: 512 blocks = o(8) x rowblock(8, 128 rows) x colslice(8, 16 cols).
// Phase 1: block computes its M[o][0:128, cs*16:+16] slice (2048 threefry
//          hashes, 8/thread) straight into LDS in MFMA B-fragment order:
//          [kk(4)][lane(64)][j(8)] bf16 = 4 KB.
// Phase 2: each wave w handles 2 row-tiles (16 rows each); A-fragments are
//          loaded as fp32 from x (L2-resident, 512 KB) and converted to bf16
//          in-register; 8 MFMAs (16x16x32 bf16) per wave; fp32 store.
// MFMA layouts (m89/m120-verified):
//   A: lane holds A[m=lane&15][k=(lane>>4)*8+j]
//   B: lane holds B[k=(lane>>4)*8+j][n=lane&15]
//   C/D: row=(lane>>4)*4+reg, col=lane&15
// ---------------------------------------------------------------------------
__global__ __launch_bounds__(256) void sem_fused(
    const float* __restrict__ x,
    const float* __restrict__ maskings,
    const float* __restrict__ theta,
    const float* __restrict__ W,
    float* __restrict__ out) {
  __shared__ uint16_t Mlds[4 * 64 * 8];  // 4 KB, B-frag order

  const int b  = blockIdx.x;
  const int cs = b & 7;          // 16-col slice
  const int rq = (b >> 3) & 7;   // 128-row block
  const int o  = b >> 6;         // structure 0..7
  const int tid = threadIdx.x;

  // ---- Phase 1: masked Bernoulli * W -> LDS B-fragments ----
  {
    const int c  = tid & 15;               // col within slice
    const int pb = tid >> 4;               // 0..15
    const int cg = cs * 16 + c;            // global col
#pragma unroll
    for (int i = 0; i < 8; ++i) {
      const int p = pb + i * 16;           // covers p = 0..127
      const uint32_t gi = ((uint32_t)o << 14) | ((uint32_t)p << 7) | (uint32_t)cg;
      const uint32_t bits = threefry_bits(gi);
      const float u = __uint_as_float((bits >> 9) | 0x3f800000u) - 1.0f;
      const float v = (u < theta[gi]) ? maskings[gi] * W[gi] : 0.0f;
      // B-frag position: kk = p>>5, lane = ((p>>3)&3)<<4 | c, j = p&7
      const int idx = (((p >> 5) * 64) + ((((p >> 3) & 3) << 4) | c)) * 8 + (p & 7);
      Mlds[idx] = f32_to_bf16_rne(v);
    }
  }
  __syncthreads();

  // ---- Phase 2: MFMA ----
  const int w    = tid >> 6;   // wave 0..3
  const int lane = tid & 63;

  const bf16x8* mf = (const bf16x8*)Mlds;
  bf16x8 bfrag[4];
#pragma unroll
  for (int kk = 0; kk < 4; ++kk) bfrag[kk] = mf[kk * 64 + lane];

  f32x4 acc[2] = {{0.f, 0.f, 0.f, 0.f}, {0.f, 0.f, 0.f, 0.f}};

  const int arow = lane & 15;          // A row within 16-row tile
  const int k0   = (lane >> 4) * 8;    // A k-offset within 32-wide kk tile
#pragma unroll
  for (int m = 0; m < 2; ++m) {
    const int rt  = rq * 8 + w * 2 + m;          // global 16-row tile 0..63
    const float* xp = x + (rt * 16 + arow) * DD + k0;
#pragma unroll
    for (int kk = 0; kk < 4; ++kk) {
      const float4 lo = *(const float4*)(xp + kk * 32);
      const float4 hi = *(const float4*)(xp + kk * 32 + 4);
      bf16x8 a;
      a[0] = (short)f32_to_bf16_rne(lo.x);
      a[1] = (short)f32_to_bf16_rne(lo.y);
      a[2] = (short)f32_to_bf16_rne(lo.z);
      a[3] = (short)f32_to_bf16_rne(lo.w);
      a[4] = (short)f32_to_bf16_rne(hi.x);
      a[5] = (short)f32_to_bf16_rne(hi.y);
      a[6] = (short)f32_to_bf16_rne(hi.z);
      a[7] = (short)f32_to_bf16_rne(hi.w);
      acc[m] = __builtin_amdgcn_mfma_f32_16x16x32_bf16(a, bfrag[kk], acc[m], 0, 0, 0);
    }
  }

  // ---- Store: C/D row=(lane>>4)*4+r, col=lane&15 ----
  const int col   = cs * 16 + (lane & 15);
  const int rbase = (lane >> 4) * 4;
#pragma unroll
  for (int m = 0; m < 2; ++m) {
    const int rt = rq * 8 + w * 2 + m;
#pragma unroll
    for (int r = 0; r < 4; ++r) {
      out[((size_t)o * NROWS + rt * 16 + rbase + r) * DD + col] = acc[m][r];
    }
  }
}

// ---------------------------------------------------------------------------

extern "C" void kernel_launch(void* const* d_in, const int* in_sizes, int n_in,
                              void* d_out, int out_size, void* d_ws, size_t ws_size,
                              hipStream_t stream) {
  (void)in_sizes; (void)n_in; (void)out_size; (void)d_ws; (void)ws_size;
  const float* x        = (const float*)d_in[0];
  const float* maskings = (const float*)d_in[1];
  const float* theta    = (const float*)d_in[2];
  const float* W        = (const float*)d_in[3];
  float* out = (float*)d_out;

  sem_fused<<<NSTRUCT * 8 * 8, 256, 0, stream>>>(x, maskings, theta, W, out);
}

// Round 2
// 62.664 us; speedup vs baseline: 1.0799x; 1.0799x over previous
//
#include <hip/hip_runtime.h>
#include <stdint.h>

#define NSTRUCT 8
#define NROWS   1024
#define DD      128

typedef short bf16x8 __attribute__((ext_vector_type(8)));  // 8 bf16 (4 VGPRs)
typedef float f32x4  __attribute__((ext_vector_type(4)));  // 4 fp32 acc

// ---------------------------------------------------------------------------
// Threefry2x32-20, JAX partitionable path: bits = out0 ^ out1 (verified R2,
// absmax 0.0 vs jax reference). u = bitcast((bits>>9)|0x3f800000) - 1.0
// ---------------------------------------------------------------------------
__device__ __forceinline__ uint32_t rotl32(uint32_t x, uint32_t d) {
  return (x << d) | (x >> (32u - d));
}

__device__ __forceinline__ uint32_t threefry_bits(uint32_t i) {
  const uint32_t ks0 = 0u;
  const uint32_t ks1 = 42u;
  const uint32_t ks2 = 0x1BD11BDAu ^ ks0 ^ ks1;
  uint32_t x0 = 0u + ks0;   // counts_hi = 0
  uint32_t x1 = i  + ks1;   // counts_lo = flat (o,p,c) index
#define TF_RND(r) { x0 += x1; x1 = rotl32(x1, r); x1 ^= x0; }
  TF_RND(13) TF_RND(15) TF_RND(26) TF_RND(6)
  x0 += ks1; x1 += ks2 + 1u;
  TF_RND(17) TF_RND(29) TF_RND(16) TF_RND(24)
  x0 += ks2; x1 += ks0 + 2u;
  TF_RND(13) TF_RND(15) TF_RND(26) TF_RND(6)
  x0 += ks0; x1 += ks1 + 3u;
  TF_RND(17) TF_RND(29) TF_RND(16) TF_RND(24)
  x0 += ks1; x1 += ks2 + 4u;
  TF_RND(13) TF_RND(15) TF_RND(26) TF_RND(6)
  x0 += ks2; x1 += ks0 + 5u;
#undef TF_RND
  return x0 ^ x1;
}

__device__ __forceinline__ uint16_t f32_to_bf16_rne(float v) {
  uint32_t fb = __float_as_uint(v);
  uint32_t lsb = (fb >> 16) & 1u;
  return (uint16_t)((fb + 0x7fffu + lsb) >> 16);
}

// ---------------------------------------------------------------------------
// build_frags: write M (masked Bernoulli * W) and x in MFMA fragment order.
// MFMA 16x16x32 bf16 layouts (m89/m120-verified):
//   A-operand: lane holds A[m=lane&15][k=(lane>>4)*8+j], j=0..7
//   B-operand: lane holds B[k=(lane>>4)*8+j][n=lane&15]
//   C/D:       lane,reg -> row=(lane>>4)*4+reg, col=lane&15
// Mb layout: [o(8)][ct(8)][kk(4)][lane(64)][j(8)]  (B-frag major) 256 KB
// xb layout: [rt(64)][kk(4)][lane(64)][j(8)]       (A-frag major) 256 KB
// Writes are 2 B/thread, consecutive -> coalesced. Reads are small gathers
// (L2/L3-resident inputs).
// ---------------------------------------------------------------------------
__global__ __launch_bounds__(256) void build_frags(
    const float* __restrict__ x,
    const float* __restrict__ maskings,
    const float* __restrict__ theta,
    const float* __restrict__ W,
    uint16_t* __restrict__ Mb,
    uint16_t* __restrict__ xb) {
  const int b = blockIdx.x;
  const int tid = threadIdx.x;
  if (b < 512) {
    // M fragment: flat = ((((o*8+ct)*4+kk)*64+lane)*8+j)
    uint32_t flat = (uint32_t)b * 256u + tid;
    uint32_t j    = flat & 7u;
    uint32_t lane = (flat >> 3) & 63u;
    uint32_t kk   = (flat >> 9) & 3u;
    uint32_t ct   = (flat >> 11) & 7u;
    uint32_t o    = flat >> 14;
    uint32_t p = kk * 32u + (lane >> 4) * 8u + j;   // K index
    uint32_t c = ct * 16u + (lane & 15u);           // N index
    uint32_t gi = (o << 14) | (p << 7) | c;         // flat (o,p,c)
    uint32_t bits = threefry_bits(gi);
    float u = __uint_as_float((bits >> 9) | 0x3f800000u) - 1.0f;
    float v = (u < theta[gi]) ? maskings[gi] * W[gi] : 0.0f;
    Mb[flat] = f32_to_bf16_rne(v);
  } else {
    // x fragment: idx = ((rt*4+kk)*64+lane)*8+j
    uint32_t idx  = (uint32_t)(b - 512) * 256u + tid;
    uint32_t j    = idx & 7u;
    uint32_t lane = (idx >> 3) & 63u;
    uint32_t kk   = (idx >> 9) & 3u;
    uint32_t rt   = idx >> 11;                      // 16-row tile 0..63
    uint32_t n = rt * 16u + (lane & 15u);           // M index (row)
    uint32_t k = kk * 32u + (lane >> 4) * 8u + j;   // K index
    xb[idx] = f32_to_bf16_rne(x[n * DD + k]);
  }
}

// ---------------------------------------------------------------------------
// sem_mfma: out[o,n,c] = sum_p x[n,p] * M[o,p,c] via bf16 MFMA, fp32 accum.
// Grid: 8 structs x 32 row-blocks (32 rows) = 256 blocks x 256 thr (4 waves).
// Wave w: row-tile rb*2+(w&1), col-tiles 4*(w>>1)..+3. No LDS, no barrier:
// fragments loaded straight from global (L2-resident). 16 MFMA/wave.
// ---------------------------------------------------------------------------
__global__ __launch_bounds__(256) void sem_mfma(
    const uint16_t* __restrict__ Mb,
    const uint16_t* __restrict__ xb,
    float* __restrict__ out) {
  const int bidx = blockIdx.x;
  const int o    = bidx >> 5;        // structure 0..7
  const int rb   = bidx & 31;        // 32-row block
  const int tid  = threadIdx.x;
  const int w    = tid >> 6;         // wave 0..3
  const int lane = tid & 63;
  const int rt_g = rb * 2 + (w & 1); // global 16-row tile 0..63
  const int ctb  = (w >> 1) * 4;     // col-tile base 0 or 4

  const bf16x8* xbv = (const bf16x8*)xb;
  const bf16x8* mbv = (const bf16x8*)Mb;

  bf16x8 a[4];
#pragma unroll
  for (int kk = 0; kk < 4; ++kk) a[kk] = xbv[(rt_g * 4 + kk) * 64 + lane];

  f32x4 acc[4] = {{0.f, 0.f, 0.f, 0.f}, {0.f, 0.f, 0.f, 0.f},
                  {0.f, 0.f, 0.f, 0.f}, {0.f, 0.f, 0.f, 0.f}};

#pragma unroll
  for (int t = 0; t < 4; ++t) {
    const int ct = ctb + t;
#pragma unroll
    for (int kk = 0; kk < 4; ++kk) {
      bf16x8 bfrag = mbv[((o * 8 + ct) * 4 + kk) * 64 + lane];
      acc[t] = __builtin_amdgcn_mfma_f32_16x16x32_bf16(a[kk], bfrag, acc[t], 0, 0, 0);
    }
  }

  // C/D layout: row = (lane>>4)*4 + reg, col = lane&15
  const int col0     = lane & 15;
  const int row_base = rb * 32 + (w & 1) * 16 + (lane >> 4) * 4;
#pragma unroll
  for (int t = 0; t < 4; ++t) {
    const int col = (ctb + t) * 16 + col0;
#pragma unroll
    for (int r = 0; r < 4; ++r) {
      out[((size_t)o * NROWS + row_base + r) * DD + col] = acc[t][r];
    }
  }
}

// ---------------------------------------------------------------------------

extern "C" void kernel_launch(void* const* d_in, const int* in_sizes, int n_in,
                              void* d_out, int out_size, void* d_ws, size_t ws_size,
                              hipStream_t stream) {
  const float* x        = (const float*)d_in[0];
  const float* maskings = (const float*)d_in[1];
  const float* theta    = (const float*)d_in[2];
  const float* W        = (const float*)d_in[3];
  float* out = (float*)d_out;

  uint16_t* Mb = (uint16_t*)d_ws;                       // 256 KB (B-frag order)
  uint16_t* xb = Mb + NSTRUCT * DD * DD;                // 256 KB (A-frag order)

  build_frags<<<1024, 256, 0, stream>>>(x, maskings, theta, W, Mb, xb);
  sem_mfma<<<NSTRUCT * 32, 256, 0, stream>>>(Mb, xb, out);
}